// Round 10
// baseline (271.405 us; speedup 1.0000x reference)
//
#include <hip/hip_runtime.h>

#define NTOK 100352   // 8*112*112
#define NPB  12544    // tokens per batch (112*112)
#define CH   256

typedef unsigned short u16;
typedef float f32x4 __attribute__((ext_vector_type(4)));
typedef short bfrag __attribute__((ext_vector_type(8)));   // 8 bf16 = 4 VGPRs

static __device__ __forceinline__ u16 f2bf(float f) {
    union { float f; unsigned u; } v; v.f = f;
    unsigned r = v.u + 0x7FFFu + ((v.u >> 16) & 1u);   // RNE
    return (u16)(r >> 16);
}
static __device__ __forceinline__ float bf2f(u16 h) {
    union { unsigned u; float f; } v; v.u = ((unsigned)h) << 16;
    return v.f;
}
static __device__ __forceinline__ unsigned pk2(float a, float b) {
    return (unsigned)f2bf(a) | ((unsigned)f2bf(b) << 16);
}
// async global->LDS, 16B/lane; LDS dest = wave-uniform base + lane*16 (linear)
static __device__ __forceinline__ void gl16(const u16* g, u16* l) {
    __builtin_amdgcn_global_load_lds(
        (const __attribute__((address_space(1))) void*)g,
        (__attribute__((address_space(3))) void*)l, 16, 0, 0);
}

// ---------------- K0: weight prep (fp32 -> bf16, fold q scale) ----------------
__global__ __launch_bounds__(256)
void swa_prep(const float* __restrict__ wq, const float* __restrict__ wk,
              const float* __restrict__ wv, const float* __restrict__ wm,
              u16* __restrict__ wcat, u16* __restrict__ wmb)
{
    int i0 = blockIdx.x * 256 + threadIdx.x;
    int stride = gridDim.x * 256;
    for (int i = i0; i < 768 * 256; i += stride) {
        int r = i >> 8, c = i & 255;
        float v;
        if (r < 256)      v = wq[r * 256 + c] * 0.0625f;      // fold d^-0.5 = 1/16
        else if (r < 512) v = wk[(r - 256) * 256 + c];
        else              v = wv[(r - 512) * 256 + c];
        wcat[i] = f2bf(v);
    }
    for (int i = i0; i < 256 * 256; i += stride) wmb[i] = f2bf(wm[i]);
}

// ---------------- K1: fused roll+LN+QKV; W-section resident, 16 waves ----------------
// grid 1176 = 3 sections x 392 strips; 1024 thr / 16 waves x 16 tokens.
// W_sec (256x256 bf16 = 128 KB) staged ONCE via global_load_lds (swizzled source,
// linear dest); one barrier; each wave computes 16 tokens x 256 ch in 4 passes.
__global__ __launch_bounds__(1024, 4)
void swa_qkv9(const float* __restrict__ x,
              const float* __restrict__ ln_g, const float* __restrict__ ln_b,
              const u16* __restrict__ wcat,
              const float* __restrict__ bq, const float* __restrict__ bk,
              const float* __restrict__ bv,
              u16* __restrict__ qbuf, u16* __restrict__ kbuf, u16* __restrict__ vbuf)
{
    __shared__ u16 wt[256 * 256];                 // 128 KB, one section

    const int tid  = threadIdx.x;
    const int lane = tid & 63;
    const int wid  = tid >> 6;                    // 0..15
    const int r16  = lane & 15, g4 = lane >> 4;
    const int sec   = blockIdx.x / 392;           // 0=q 1=k 2=v
    const int strip = blockIdx.x % 392;
    const int tok   = strip * 256 + wid * 16 + r16;   // this lane's token

    // ---- stage W section: 8 rounds x (1024 thr x 16B); XOR-swizzle via SOURCE ----
    #pragma unroll
    for (int rr = 0; rr < 8; ++rr) {
        int o   = (tid + rr * 1024) * 16;         // linear byte offset in wt
        int row = o >> 9;                         // 512 B per 256-bf16 row
        int cp  = (o >> 4) & 31;                  // 16B chunk within row
        int c   = (cp & 24) | ((cp & 7) ^ (row & 7));
        gl16(wcat + (size_t)(sec * 256 + row) * CH + c * 8, wt + o / 2);
    }

    // ---- roll + LN -> bx (MFMA B-fragment for this lane's token) ----
    bfrag bx[8];
    {
        int b_  = tok / NPB, rem = tok - b_ * NPB;
        int h = rem / 112, w = rem - h * 112;
        int h0 = h - 3 + ((h < 3) ? 112 : 0);     // shifted read
        int w0 = w - 3 + ((w < 3) ? 112 : 0);
        const float* rp = x + (size_t)(b_ * NPB + h0 * 112 + w0) * CH + g4 * 8;
        f32x4 xv[16];
        #pragma unroll
        for (int kb = 0; kb < 8; ++kb) {
            xv[kb * 2]     = *reinterpret_cast<const f32x4*>(rp + kb * 32);
            xv[kb * 2 + 1] = *reinterpret_cast<const f32x4*>(rp + kb * 32 + 4);
        }
        float s = 0.f, sq = 0.f;
        #pragma unroll
        for (int q = 0; q < 16; ++q) {
            s  += xv[q][0] + xv[q][1] + xv[q][2] + xv[q][3];
            sq += xv[q][0]*xv[q][0] + xv[q][1]*xv[q][1] + xv[q][2]*xv[q][2] + xv[q][3]*xv[q][3];
        }
        s  += __shfl_xor(s, 16); sq += __shfl_xor(sq, 16);   // reduce over g4 group
        s  += __shfl_xor(s, 32); sq += __shfl_xor(sq, 32);
        float mu  = s * (1.0f / 256.0f);
        float var = sq * (1.0f / 256.0f) - mu * mu;
        float inv = 1.0f / sqrtf(var + 1e-5f);
        #pragma unroll
        for (int kb = 0; kb < 8; ++kb) {
            const float* gp = ln_g + kb * 32 + g4 * 8;
            const float* bp = ln_b + kb * 32 + g4 * 8;
            f32x4 g0 = *reinterpret_cast<const f32x4*>(gp);
            f32x4 g1 = *reinterpret_cast<const f32x4*>(gp + 4);
            f32x4 b0 = *reinterpret_cast<const f32x4*>(bp);
            f32x4 b1 = *reinterpret_cast<const f32x4*>(bp + 4);
            f32x4 a0 = xv[kb * 2], a1 = xv[kb * 2 + 1];
            union { unsigned u[4]; bfrag f; } cv;
            cv.u[0] = pk2((a0[0]-mu)*inv*g0[0]+b0[0], (a0[1]-mu)*inv*g0[1]+b0[1]);
            cv.u[1] = pk2((a0[2]-mu)*inv*g0[2]+b0[2], (a0[3]-mu)*inv*g0[3]+b0[3]);
            cv.u[2] = pk2((a1[0]-mu)*inv*g1[0]+b1[0], (a1[1]-mu)*inv*g1[1]+b1[1]);
            cv.u[3] = pk2((a1[2]-mu)*inv*g1[2]+b1[2], (a1[3]-mu)*inv*g1[3]+b1[3]);
            bx[kb] = cv.f;
        }
    }

    u16*         outp = (sec == 0) ? qbuf : (sec == 1) ? kbuf : vbuf;
    const float* bsp  = (sec == 0) ? bq : (sec == 1) ? bk : bv;
    const float  bsc  = (sec == 0) ? 0.0625f : 1.0f;

    __syncthreads();                              // W staged; only barrier in kernel

    #pragma unroll
    for (int p = 0; p < 4; ++p) {                 // 4 channel passes x 64 ch
        f32x4 acc[4];
        #pragma unroll
        for (int ct = 0; ct < 4; ++ct) acc[ct] = (f32x4)0.f;
        #pragma unroll
        for (int kk = 0; kk < 8; ++kk) {
            bfrag af[4];
            #pragma unroll
            for (int ct = 0; ct < 4; ++ct) {
                int row = p * 64 + ct * 16 + r16;
                int cc  = kk * 4 + g4;
                int cp  = (cc & 24) | ((cc & 7) ^ (row & 7));
                af[ct]  = *reinterpret_cast<const bfrag*>((const char*)wt + row * 512 + cp * 16);
            }
            #pragma unroll
            for (int ct = 0; ct < 4; ++ct)
                acc[ct] = __builtin_amdgcn_mfma_f32_16x16x32_bf16(af[ct], bx[kk], acc[ct], 0, 0, 0);
        }
        #pragma unroll
        for (int ct = 0; ct < 4; ++ct) {
            int ch = p * 64 + ct * 16 + g4 * 4;
            f32x4 bb = *reinterpret_cast<const f32x4*>(bsp + ch);
            uint2 pkk;
            pkk.x = pk2(acc[ct][0] + bb[0] * bsc, acc[ct][1] + bb[1] * bsc);
            pkk.y = pk2(acc[ct][2] + bb[2] * bsc, acc[ct][3] + bb[3] * bsc);
            *reinterpret_cast<uint2*>(outp + (size_t)tok * CH + ch) = pkk;
        }
    }
}

// ---------------- K2: local attention + on-the-fly k-normalization ----------------
__global__ __launch_bounds__(256)
void swa_attn(const u16* qbuf, const u16* kbuf, const u16* vbuf, u16* obuf)
{
    __shared__ float plds[4][16][17];
    const int tid  = threadIdx.x;
    const int lane = tid & 63;
    const int wid  = tid >> 6;
    const int win  = blockIdx.x * 4 + wid;
    const int iw   = win % 1792;
    const int base = win * 7;
    const int r16  = lane & 15;
    const int g4   = lane >> 4;

    int qrow = base + r16; if (qrow > NTOK - 1) qrow = NTOK - 1;
    int krow = base - 7 + r16; if (krow < 0) krow = 0;
    const u16* qp = qbuf + (size_t)qrow * CH + g4 * 8;
    const u16* kp = kbuf + (size_t)krow * CH + g4 * 8;

    bfrag kf[8];
    #pragma unroll
    for (int kk = 0; kk < 8; ++kk) kf[kk] = *reinterpret_cast<const bfrag*>(kp + kk * 32);
    float sq = 0.f;
    #pragma unroll
    for (int kk = 0; kk < 8; ++kk)
        #pragma unroll
        for (int e = 0; e < 8; ++e) { float kv = bf2f((u16)kf[kk][e]); sq += kv * kv; }
    sq += __shfl_xor(sq, 16); sq += __shfl_xor(sq, 32);
    float invk = 1.0f / fmaxf(sqrtf(sq), 1e-12f);

    f32x4 s4 = {0.f, 0.f, 0.f, 0.f};
    #pragma unroll
    for (int kk = 0; kk < 8; ++kk) {
        bfrag a = *reinterpret_cast<const bfrag*>(qp + kk * 32);
        s4 = __builtin_amdgcn_mfma_f32_16x16x32_bf16(a, kf[kk], s4, 0, 0, 0);
    }

    const int  j     = r16;
    const bool first = (iw == 0);
    #pragma unroll
    for (int rr = 0; rr < 4; ++rr) {
        int i = g4 * 4 + rr;
        float s = s4[rr] * invk;
        if (j == i + 7) s = -5.0e4f;
        if (j > i + 7 || j >= 14 || (first && j < 7)) s = -3.0e38f;
        s4[rr] = s;
    }
    f32x4 mx = s4;
    #pragma unroll
    for (int off = 8; off; off >>= 1) {
        #pragma unroll
        for (int rr = 0; rr < 4; ++rr) mx[rr] = fmaxf(mx[rr], __shfl_xor(mx[rr], off));
    }
    f32x4 p;
    #pragma unroll
    for (int rr = 0; rr < 4; ++rr) p[rr] = __expf(s4[rr] - mx[rr]);
    f32x4 sm = p;
    #pragma unroll
    for (int off = 8; off; off >>= 1) {
        #pragma unroll
        for (int rr = 0; rr < 4; ++rr) sm[rr] += __shfl_xor(sm[rr], off);
    }
    #pragma unroll
    for (int rr = 0; rr < 4; ++rr) plds[wid][g4 * 4 + rr][j] = p[rr] / sm[rr];
    __syncthreads();

    f32x4 zero4 = {0.f, 0.f, 0.f, 0.f};
    f32x4 oa[7];
    #pragma unroll
    for (int i = 0; i < 7; ++i) oa[i] = zero4;
    for (int jj = 0; jj < 14; ++jj) {
        int vrow = base - 7 + jj;
        if (vrow < 0) vrow = 0;
        ushort4 vr = *reinterpret_cast<const ushort4*>(vbuf + (size_t)vrow * CH + lane * 4);
        f32x4 vvv; vvv[0] = bf2f(vr.x); vvv[1] = bf2f(vr.y); vvv[2] = bf2f(vr.z); vvv[3] = bf2f(vr.w);
        #pragma unroll
        for (int i = 0; i < 7; ++i) {
            float pp = plds[wid][i][jj];
            oa[i][0] += pp * vvv[0]; oa[i][1] += pp * vvv[1];
            oa[i][2] += pp * vvv[2]; oa[i][3] += pp * vvv[3];
        }
    }
    #pragma unroll
    for (int i = 0; i < 7; ++i) {
        ushort4 o; o.x = f2bf(oa[i][0]); o.y = f2bf(oa[i][1]); o.z = f2bf(oa[i][2]); o.w = f2bf(oa[i][3]);
        *reinterpret_cast<ushort4*>(obuf + (size_t)(base + i) * CH + lane * 4) = o;
    }
}

// ---------------- K3: unshift + residual + LN + MLP(GELU) + add ----------------
__global__ __launch_bounds__(256)
void swa_mlp4(const float* __restrict__ x, const u16* __restrict__ abuf,
              const float* __restrict__ ln_g, const float* __restrict__ ln_b,
              const u16* __restrict__ wmb, const float* __restrict__ mbias,
              float* __restrict__ out)
{
    __shared__ u16   xs[32][264];
    __shared__ float rsd[32][260];
    __shared__ float bias[256];
    const int tid  = threadIdx.x;
    const int lane = tid & 63;
    const int wid  = tid >> 6;
    const int tok0 = blockIdx.x * 32;
    const int r16  = lane & 15;
    const int g4   = lane >> 4;

    if (tid < 256) bias[tid] = mbias[tid];
    f32x4 lg = *reinterpret_cast<const f32x4*>(ln_g + lane * 4);
    f32x4 lb = *reinterpret_cast<const f32x4*>(ln_b + lane * 4);

    for (int it = 0; it < 8; ++it) {
        int tt  = wid * 8 + it;
        int tok = tok0 + tt;
        int b_  = tok / NPB, rem = tok - b_ * NPB;
        int h = rem / 112, w = rem - h * 112;
        int hs = h + 3;  if (hs >= 112) hs -= 112;
        int ws_ = w + 3; if (ws_ >= 112) ws_ -= 112;
        const u16* arow = abuf + (size_t)(b_ * NPB + hs * 112 + ws_) * CH;
        ushort4 av = *reinterpret_cast<const ushort4*>(arow + lane * 4);
        f32x4 xv = *reinterpret_cast<const f32x4*>(x + (size_t)tok * CH + lane * 4);
        f32x4 rv;
        rv[0] = xv[0] + bf2f(av.x); rv[1] = xv[1] + bf2f(av.y);
        rv[2] = xv[2] + bf2f(av.z); rv[3] = xv[3] + bf2f(av.w);
        *reinterpret_cast<f32x4*>(&rsd[tt][lane * 4]) = rv;
        float s  = rv[0] + rv[1] + rv[2] + rv[3];
        float sq = rv[0]*rv[0] + rv[1]*rv[1] + rv[2]*rv[2] + rv[3]*rv[3];
        #pragma unroll
        for (int m = 32; m; m >>= 1) { s += __shfl_xor(s, m); sq += __shfl_xor(sq, m); }
        float mu  = s * (1.0f / 256.0f);
        float var = sq * (1.0f / 256.0f) - mu * mu;
        float inv = 1.0f / sqrtf(var + 1e-5f);
        ushort4 o;
        o.x = f2bf((rv[0] - mu) * inv * lg[0] + lb[0]);
        o.y = f2bf((rv[1] - mu) * inv * lg[1] + lb[1]);
        o.z = f2bf((rv[2] - mu) * inv * lg[2] + lb[2]);
        o.w = f2bf((rv[3] - mu) * inv * lg[3] + lb[3]);
        *reinterpret_cast<ushort4*>(&xs[tt][lane * 4]) = o;
    }
    __syncthreads();

    f32x4 acc[4][2];
    #pragma unroll
    for (int i = 0; i < 4; ++i) { acc[i][0] = (f32x4)0.f; acc[i][1] = (f32x4)0.f; }

    #pragma unroll
    for (int kk = 0; kk < 8; ++kk) {
        bfrag b0 = *reinterpret_cast<const bfrag*>(&xs[r16][kk * 32 + g4 * 8]);
        bfrag b1 = *reinterpret_cast<const bfrag*>(&xs[16 + r16][kk * 32 + g4 * 8]);
        #pragma unroll
        for (int ct = 0; ct < 4; ++ct) {
            bfrag wf = *reinterpret_cast<const bfrag*>(wmb + (size_t)(wid * 64 + ct * 16 + r16) * CH + kk * 32 + g4 * 8);
            acc[ct][0] = __builtin_amdgcn_mfma_f32_16x16x32_bf16(wf, b0, acc[ct][0], 0, 0, 0);
            acc[ct][1] = __builtin_amdgcn_mfma_f32_16x16x32_bf16(wf, b1, acc[ct][1], 0, 0, 0);
        }
    }

    #pragma unroll
    for (int ct = 0; ct < 4; ++ct) {
        int ch = wid * 64 + ct * 16 + g4 * 4;
        f32x4 bb = *reinterpret_cast<const f32x4*>(&bias[ch]);
        #pragma unroll
        for (int rt = 0; rt < 2; ++rt) {
            int tokL = rt * 16 + r16;
            f32x4 rb = *reinterpret_cast<const f32x4*>(&rsd[tokL][ch]);
            f32x4 vv;
            #pragma unroll
            for (int rr = 0; rr < 4; ++rr) {
                float val = acc[ct][rt][rr] + bb[rr];
                vv[rr] = 0.5f * val * (1.0f + erff(val * 0.70710678118654752f)) + rb[rr];
            }
            *reinterpret_cast<f32x4*>(out + (size_t)(tok0 + tokL) * CH + ch) = vv;
        }
    }
}

extern "C" void kernel_launch(void* const* d_in, const int* in_sizes, int n_in,
                              void* d_out, int out_size, void* d_ws, size_t ws_size,
                              hipStream_t stream)
{
    const float* x     = (const float*)d_in[0];
    const float* ln_g  = (const float*)d_in[1];
    const float* ln_b  = (const float*)d_in[2];
    const float* wq_w  = (const float*)d_in[3];
    const float* wq_b  = (const float*)d_in[4];
    const float* wk_w  = (const float*)d_in[5];
    const float* wk_b  = (const float*)d_in[6];
    const float* wv_w  = (const float*)d_in[7];
    const float* wv_b  = (const float*)d_in[8];
    const float* mlp_w = (const float*)d_in[9];
    const float* mlp_b = (const float*)d_in[10];

    char* ws = (char*)d_ws;
    u16* wcat = (u16*)ws;                       // 768*256 bf16
    u16* wmb  = (u16*)(ws + 393216);            // 256*256 bf16
    u16* qbuf = (u16*)(ws + 524288);            // q; attn output overwrites it
    u16* kbuf = (u16*)d_out;                    // k,v live in d_out until K3 rewrites it
    u16* vbuf = (u16*)d_out + (size_t)NTOK * CH;

    swa_prep <<<256,  256,  0, stream>>>(wq_w, wk_w, wv_w, mlp_w, wcat, wmb);
    swa_qkv9 <<<1176, 1024, 0, stream>>>(x, ln_g, ln_b, wcat, wq_b, wk_b, wv_b, qbuf, kbuf, vbuf);
    swa_attn <<<3584, 256,  0, stream>>>(qbuf, kbuf, vbuf, qbuf);
    swa_mlp4 <<<3136, 256,  0, stream>>>(x, qbuf, ln_g, ln_b, wmb, mlp_b, (float*)d_out);
}

// Round 11
// 269.613 us; speedup vs baseline: 1.0066x; 1.0066x over previous
//
#include <hip/hip_runtime.h>

#define NTOK 100352   // 8*112*112
#define NPB  12544    // tokens per batch (112*112)
#define CH   256

typedef unsigned short u16;
typedef float f32x4 __attribute__((ext_vector_type(4)));
typedef short bfrag __attribute__((ext_vector_type(8)));   // 8 bf16 = 4 VGPRs

static __device__ __forceinline__ u16 f2bf(float f) {
    union { float f; unsigned u; } v; v.f = f;
    unsigned r = v.u + 0x7FFFu + ((v.u >> 16) & 1u);   // RNE
    return (u16)(r >> 16);
}
static __device__ __forceinline__ float bf2f(u16 h) {
    union { unsigned u; float f; } v; v.u = ((unsigned)h) << 16;
    return v.f;
}
static __device__ __forceinline__ unsigned pk2(float a, float b) {
    return (unsigned)f2bf(a) | ((unsigned)f2bf(b) << 16);
}
// async global->LDS, 16B/lane; LDS dest = wave-uniform base + lane*16 (linear)
static __device__ __forceinline__ void gl16(const u16* g, u16* l) {
    __builtin_amdgcn_global_load_lds(
        (const __attribute__((address_space(1))) void*)g,
        (__attribute__((address_space(3))) void*)l, 16, 0, 0);
}

// ---------------- K0: weight prep (fp32 -> bf16, fold q scale) ----------------
__global__ __launch_bounds__(256)
void swa_prep(const float* __restrict__ wq, const float* __restrict__ wk,
              const float* __restrict__ wv, const float* __restrict__ wm,
              u16* __restrict__ wcat, u16* __restrict__ wmb)
{
    int i0 = blockIdx.x * 256 + threadIdx.x;
    int stride = gridDim.x * 256;
    for (int i = i0; i < 768 * 256; i += stride) {
        int r = i >> 8, c = i & 255;
        float v;
        if (r < 256)      v = wq[r * 256 + c] * 0.0625f;      // fold d^-0.5 = 1/16
        else if (r < 512) v = wk[(r - 256) * 256 + c];
        else              v = wv[(r - 512) * 256 + c];
        wcat[i] = f2bf(v);
    }
    for (int i = i0; i < 256 * 256; i += stride) wmb[i] = f2bf(wm[i]);
}

// ---------------- K1a: roll + LN -> xn (bf16), one wave per token ----------------
__global__ __launch_bounds__(256)
void swa_ln(const float* __restrict__ x,
            const float* __restrict__ ln_g, const float* __restrict__ ln_b,
            u16* __restrict__ xn)
{
    const int lane = threadIdx.x & 63;
    const int wid  = threadIdx.x >> 6;
    f32x4 lg = *reinterpret_cast<const f32x4*>(ln_g + lane * 4);
    f32x4 lb = *reinterpret_cast<const f32x4*>(ln_b + lane * 4);

    const int wtok0 = (blockIdx.x * 4 + wid) * 16;
    for (int i = 0; i < 16; ++i) {
        int tok = wtok0 + i;
        int b_  = tok / NPB;
        int rem = tok - b_ * NPB;
        int h = rem / 112, w = rem - h * 112;
        int h0 = h - 3 + ((h < 3) ? 112 : 0);         // shifted read
        int w0 = w - 3 + ((w < 3) ? 112 : 0);
        f32x4 v = *reinterpret_cast<const f32x4*>(x + (size_t)(b_ * NPB + h0 * 112 + w0) * CH + lane * 4);
        float s  = v[0] + v[1] + v[2] + v[3];
        float sq = v[0]*v[0] + v[1]*v[1] + v[2]*v[2] + v[3]*v[3];
        #pragma unroll
        for (int m = 1; m < 64; m <<= 1) { s += __shfl_xor(s, m); sq += __shfl_xor(sq, m); }
        float mu  = s * (1.0f / 256.0f);
        float var = sq * (1.0f / 256.0f) - mu * mu;
        float inv = 1.0f / sqrtf(var + 1e-5f);
        uint2 p;
        p.x = pk2((v[0] - mu) * inv * lg[0] + lb[0], (v[1] - mu) * inv * lg[1] + lb[1]);
        p.y = pk2((v[2] - mu) * inv * lg[2] + lb[2], (v[3] - mu) * inv * lg[3] + lb[3]);
        *reinterpret_cast<uint2*>(xn + (size_t)tok * CH + lane * 4) = p;
    }
}

// ---------------- K1b: k,v GEMM; W-half resident in LDS, barrier-free loop --------
// 1568 blocks = 4 types (k0,k1,v0,v1 halves) x 392 strips x 256 tokens; 512 thr.
// Stage W-half (128x256 = 64 KB) once via gl_lds (swizzled source, linear dest),
// ONE barrier, then 8 independent waves x 32 tokens, bx in regs, af from LDS.
__global__ __launch_bounds__(512)
void swa_kv(const u16* __restrict__ xn, const u16* __restrict__ wcat,
            const float* __restrict__ bk, const float* __restrict__ bv,
            u16* __restrict__ kbuf, u16* __restrict__ vbuf)
{
    __shared__ u16 wt[128 * 256];                 // 64 KB

    const int tid  = threadIdx.x;
    const int lane = tid & 63;
    const int wid  = tid >> 6;
    const int r16  = lane & 15, g4 = lane >> 4;
    const int swz   = (blockIdx.x & 7) * 196 + (blockIdx.x >> 3);   // 1568 = 8*196
    const int type  = swz / 392;                  // 0,1 = k halves; 2,3 = v halves
    const int strip = swz % 392;
    const int sec   = 1 + (type >> 1);
    const int half  = type & 1;
    const int tok0w = strip * 256 + wid * 32;
    const int wrow0 = sec * 256 + half * 128;

    #pragma unroll
    for (int rr2 = 0; rr2 < 8; ++rr2) {
        int o   = (tid + rr2 * 512) * 16;
        int row = o >> 9;
        int cp  = (o >> 4) & 31;
        int c   = (cp & 24) | ((cp & 7) ^ (row & 7));
        gl16(wcat + (size_t)(wrow0 + row) * CH + c * 8, wt + o / 2);
    }

    bfrag bx[2][8];
    #pragma unroll
    for (int fj = 0; fj < 2; ++fj) {
        const u16* xp = xn + (size_t)(tok0w + fj * 16 + r16) * CH + g4 * 8;
        #pragma unroll
        for (int kb = 0; kb < 8; ++kb)
            bx[fj][kb] = *reinterpret_cast<const bfrag*>(xp + kb * 32);
    }

    u16*         outp = (sec == 1) ? kbuf : vbuf;
    const float* bsp  = (sec == 1) ? bk : bv;

    __syncthreads();                              // W staged; only barrier

    #pragma unroll
    for (int p = 0; p < 4; ++p) {                 // 4 passes x 32 ch
        f32x4 acc[2][2];
        #pragma unroll
        for (int ct = 0; ct < 2; ++ct) { acc[ct][0] = (f32x4)0.f; acc[ct][1] = (f32x4)0.f; }
        #pragma unroll
        for (int kk = 0; kk < 8; ++kk) {
            bfrag af[2];
            #pragma unroll
            for (int ct = 0; ct < 2; ++ct) {
                int row = p * 32 + ct * 16 + r16;
                int cc  = kk * 4 + g4;
                int cp  = (cc & 24) | ((cc & 7) ^ (row & 7));
                af[ct]  = *reinterpret_cast<const bfrag*>((const char*)wt + row * 512 + cp * 16);
            }
            #pragma unroll
            for (int ct = 0; ct < 2; ++ct) {
                acc[ct][0] = __builtin_amdgcn_mfma_f32_16x16x32_bf16(af[ct], bx[0][kk], acc[ct][0], 0, 0, 0);
                acc[ct][1] = __builtin_amdgcn_mfma_f32_16x16x32_bf16(af[ct], bx[1][kk], acc[ct][1], 0, 0, 0);
            }
        }
        #pragma unroll
        for (int ct = 0; ct < 2; ++ct) {
            int ch = half * 128 + p * 32 + ct * 16 + g4 * 4;   // section-local channel
            f32x4 bb = *reinterpret_cast<const f32x4*>(bsp + ch);
            #pragma unroll
            for (int fj = 0; fj < 2; ++fj) {
                int tok = tok0w + fj * 16 + r16;
                uint2 pkk;
                pkk.x = pk2(acc[ct][fj][0] + bb[0], acc[ct][fj][1] + bb[1]);
                pkk.y = pk2(acc[ct][fj][2] + bb[2], acc[ct][fj][3] + bb[3]);
                *reinterpret_cast<uint2*>(outp + (size_t)tok * CH + ch) = pkk;
            }
        }
    }
}

// ---------------- K1c: q GEMM in-place over xn; full section resident ------------
// 392 blocks x 256 tokens; 512 thr. Safe in-place: all xn reads precede the single
// barrier; q stores after. (swa_kv already finished reading xn — stream order.)
__global__ __launch_bounds__(512)
void swa_q(u16* xnq, const u16* __restrict__ wcat, const float* __restrict__ bq)
{
    __shared__ u16 wt[256 * 256];                 // 128 KB (q section)

    const int tid  = threadIdx.x;
    const int lane = tid & 63;
    const int wid  = tid >> 6;
    const int r16  = lane & 15, g4 = lane >> 4;
    const int strip = (blockIdx.x & 7) * 49 + (blockIdx.x >> 3);   // 392 = 8*49
    const int tok0w = strip * 256 + wid * 32;

    #pragma unroll
    for (int rr2 = 0; rr2 < 16; ++rr2) {
        int o   = (tid + rr2 * 512) * 16;
        int row = o >> 9;
        int cp  = (o >> 4) & 31;
        int c   = (cp & 24) | ((cp & 7) ^ (row & 7));
        gl16(wcat + (size_t)row * CH + c * 8, wt + o / 2);
    }

    bfrag bx[2][8];
    #pragma unroll
    for (int fj = 0; fj < 2; ++fj) {
        const u16* xp = xnq + (size_t)(tok0w + fj * 16 + r16) * CH + g4 * 8;
        #pragma unroll
        for (int kb = 0; kb < 8; ++kb)
            bx[fj][kb] = *reinterpret_cast<const bfrag*>(xp + kb * 32);
    }

    __syncthreads();                              // W staged + all xn reads done

    #pragma unroll
    for (int p = 0; p < 8; ++p) {                 // 8 passes x 32 ch
        f32x4 acc[2][2];
        #pragma unroll
        for (int ct = 0; ct < 2; ++ct) { acc[ct][0] = (f32x4)0.f; acc[ct][1] = (f32x4)0.f; }
        #pragma unroll
        for (int kk = 0; kk < 8; ++kk) {
            bfrag af[2];
            #pragma unroll
            for (int ct = 0; ct < 2; ++ct) {
                int row = p * 32 + ct * 16 + r16;
                int cc  = kk * 4 + g4;
                int cp  = (cc & 24) | ((cc & 7) ^ (row & 7));
                af[ct]  = *reinterpret_cast<const bfrag*>((const char*)wt + row * 512 + cp * 16);
            }
            #pragma unroll
            for (int ct = 0; ct < 2; ++ct) {
                acc[ct][0] = __builtin_amdgcn_mfma_f32_16x16x32_bf16(af[ct], bx[0][kk], acc[ct][0], 0, 0, 0);
                acc[ct][1] = __builtin_amdgcn_mfma_f32_16x16x32_bf16(af[ct], bx[1][kk], acc[ct][1], 0, 0, 0);
            }
        }
        #pragma unroll
        for (int ct = 0; ct < 2; ++ct) {
            int ch = p * 32 + ct * 16 + g4 * 4;
            f32x4 bb = *reinterpret_cast<const f32x4*>(bq + ch);
            #pragma unroll
            for (int fj = 0; fj < 2; ++fj) {
                int tok = tok0w + fj * 16 + r16;
                uint2 pkk;
                pkk.x = pk2(acc[ct][fj][0] + bb[0] * 0.0625f, acc[ct][fj][1] + bb[1] * 0.0625f);
                pkk.y = pk2(acc[ct][fj][2] + bb[2] * 0.0625f, acc[ct][fj][3] + bb[3] * 0.0625f);
                *reinterpret_cast<uint2*>(xnq + (size_t)tok * CH + ch) = pkk;
            }
        }
    }
}

// ---------------- K2: local attention + on-the-fly k-normalization ----------------
__global__ __launch_bounds__(256)
void swa_attn(const u16* qbuf, const u16* kbuf, const u16* vbuf, u16* obuf)
{
    __shared__ float plds[4][16][17];
    const int tid  = threadIdx.x;
    const int lane = tid & 63;
    const int wid  = tid >> 6;
    const int win  = blockIdx.x * 4 + wid;
    const int iw   = win % 1792;
    const int base = win * 7;
    const int r16  = lane & 15;
    const int g4   = lane >> 4;

    int qrow = base + r16; if (qrow > NTOK - 1) qrow = NTOK - 1;
    int krow = base - 7 + r16; if (krow < 0) krow = 0;
    const u16* qp = qbuf + (size_t)qrow * CH + g4 * 8;
    const u16* kp = kbuf + (size_t)krow * CH + g4 * 8;

    bfrag kf[8];
    #pragma unroll
    for (int kk = 0; kk < 8; ++kk) kf[kk] = *reinterpret_cast<const bfrag*>(kp + kk * 32);
    float sq = 0.f;
    #pragma unroll
    for (int kk = 0; kk < 8; ++kk)
        #pragma unroll
        for (int e = 0; e < 8; ++e) { float kv = bf2f((u16)kf[kk][e]); sq += kv * kv; }
    sq += __shfl_xor(sq, 16); sq += __shfl_xor(sq, 32);
    float invk = 1.0f / fmaxf(sqrtf(sq), 1e-12f);

    f32x4 s4 = {0.f, 0.f, 0.f, 0.f};
    #pragma unroll
    for (int kk = 0; kk < 8; ++kk) {
        bfrag a = *reinterpret_cast<const bfrag*>(qp + kk * 32);
        s4 = __builtin_amdgcn_mfma_f32_16x16x32_bf16(a, kf[kk], s4, 0, 0, 0);
    }

    const int  j     = r16;
    const bool first = (iw == 0);
    #pragma unroll
    for (int rr = 0; rr < 4; ++rr) {
        int i = g4 * 4 + rr;
        float s = s4[rr] * invk;
        if (j == i + 7) s = -5.0e4f;
        if (j > i + 7 || j >= 14 || (first && j < 7)) s = -3.0e38f;
        s4[rr] = s;
    }
    f32x4 mx = s4;
    #pragma unroll
    for (int off = 8; off; off >>= 1) {
        #pragma unroll
        for (int rr = 0; rr < 4; ++rr) mx[rr] = fmaxf(mx[rr], __shfl_xor(mx[rr], off));
    }
    f32x4 p;
    #pragma unroll
    for (int rr = 0; rr < 4; ++rr) p[rr] = __expf(s4[rr] - mx[rr]);
    f32x4 sm = p;
    #pragma unroll
    for (int off = 8; off; off >>= 1) {
        #pragma unroll
        for (int rr = 0; rr < 4; ++rr) sm[rr] += __shfl_xor(sm[rr], off);
    }
    #pragma unroll
    for (int rr = 0; rr < 4; ++rr) plds[wid][g4 * 4 + rr][j] = p[rr] / sm[rr];
    __syncthreads();

    f32x4 zero4 = {0.f, 0.f, 0.f, 0.f};
    f32x4 oa[7];
    #pragma unroll
    for (int i = 0; i < 7; ++i) oa[i] = zero4;
    for (int jj = 0; jj < 14; ++jj) {
        int vrow = base - 7 + jj;
        if (vrow < 0) vrow = 0;
        ushort4 vr = *reinterpret_cast<const ushort4*>(vbuf + (size_t)vrow * CH + lane * 4);
        f32x4 vvv; vvv[0] = bf2f(vr.x); vvv[1] = bf2f(vr.y); vvv[2] = bf2f(vr.z); vvv[3] = bf2f(vr.w);
        #pragma unroll
        for (int i = 0; i < 7; ++i) {
            float pp = plds[wid][i][jj];
            oa[i][0] += pp * vvv[0]; oa[i][1] += pp * vvv[1];
            oa[i][2] += pp * vvv[2]; oa[i][3] += pp * vvv[3];
        }
    }
    #pragma unroll
    for (int i = 0; i < 7; ++i) {
        ushort4 o; o.x = f2bf(oa[i][0]); o.y = f2bf(oa[i][1]); o.z = f2bf(oa[i][2]); o.w = f2bf(oa[i][3]);
        *reinterpret_cast<ushort4*>(obuf + (size_t)(base + i) * CH + lane * 4) = o;
    }
}

// ---------------- K3: unshift + residual + LN + MLP(GELU) + add ----------------
__global__ __launch_bounds__(256)
void swa_mlp4(const float* __restrict__ x, const u16* __restrict__ abuf,
              const float* __restrict__ ln_g, const float* __restrict__ ln_b,
              const u16* __restrict__ wmb, const float* __restrict__ mbias,
              float* __restrict__ out)
{
    __shared__ u16   xs[32][264];
    __shared__ float rsd[32][260];
    __shared__ float bias[256];
    const int tid  = threadIdx.x;
    const int lane = tid & 63;
    const int wid  = tid >> 6;
    const int tok0 = blockIdx.x * 32;
    const int r16  = lane & 15;
    const int g4   = lane >> 4;

    if (tid < 256) bias[tid] = mbias[tid];
    f32x4 lg = *reinterpret_cast<const f32x4*>(ln_g + lane * 4);
    f32x4 lb = *reinterpret_cast<const f32x4*>(ln_b + lane * 4);

    for (int it = 0; it < 8; ++it) {
        int tt  = wid * 8 + it;
        int tok = tok0 + tt;
        int b_  = tok / NPB, rem = tok - b_ * NPB;
        int h = rem / 112, w = rem - h * 112;
        int hs = h + 3;  if (hs >= 112) hs -= 112;
        int ws_ = w + 3; if (ws_ >= 112) ws_ -= 112;
        const u16* arow = abuf + (size_t)(b_ * NPB + hs * 112 + ws_) * CH;
        ushort4 av = *reinterpret_cast<const ushort4*>(arow + lane * 4);
        f32x4 xv = *reinterpret_cast<const f32x4*>(x + (size_t)tok * CH + lane * 4);
        f32x4 rv;
        rv[0] = xv[0] + bf2f(av.x); rv[1] = xv[1] + bf2f(av.y);
        rv[2] = xv[2] + bf2f(av.z); rv[3] = xv[3] + bf2f(av.w);
        *reinterpret_cast<f32x4*>(&rsd[tt][lane * 4]) = rv;
        float s  = rv[0] + rv[1] + rv[2] + rv[3];
        float sq = rv[0]*rv[0] + rv[1]*rv[1] + rv[2]*rv[2] + rv[3]*rv[3];
        #pragma unroll
        for (int m = 32; m; m >>= 1) { s += __shfl_xor(s, m); sq += __shfl_xor(sq, m); }
        float mu  = s * (1.0f / 256.0f);
        float var = sq * (1.0f / 256.0f) - mu * mu;
        float inv = 1.0f / sqrtf(var + 1e-5f);
        ushort4 o;
        o.x = f2bf((rv[0] - mu) * inv * lg[0] + lb[0]);
        o.y = f2bf((rv[1] - mu) * inv * lg[1] + lb[1]);
        o.z = f2bf((rv[2] - mu) * inv * lg[2] + lb[2]);
        o.w = f2bf((rv[3] - mu) * inv * lg[3] + lb[3]);
        *reinterpret_cast<ushort4*>(&xs[tt][lane * 4]) = o;
    }
    __syncthreads();

    f32x4 acc[4][2];
    #pragma unroll
    for (int i = 0; i < 4; ++i) { acc[i][0] = (f32x4)0.f; acc[i][1] = (f32x4)0.f; }

    #pragma unroll
    for (int kk = 0; kk < 8; ++kk) {
        bfrag b0 = *reinterpret_cast<const bfrag*>(&xs[r16][kk * 32 + g4 * 8]);
        bfrag b1 = *reinterpret_cast<const bfrag*>(&xs[16 + r16][kk * 32 + g4 * 8]);
        #pragma unroll
        for (int ct = 0; ct < 4; ++ct) {
            bfrag wf = *reinterpret_cast<const bfrag*>(wmb + (size_t)(wid * 64 + ct * 16 + r16) * CH + kk * 32 + g4 * 8);
            acc[ct][0] = __builtin_amdgcn_mfma_f32_16x16x32_bf16(wf, b0, acc[ct][0], 0, 0, 0);
            acc[ct][1] = __builtin_amdgcn_mfma_f32_16x16x32_bf16(wf, b1, acc[ct][1], 0, 0, 0);
        }
    }

    #pragma unroll
    for (int ct = 0; ct < 4; ++ct) {
        int ch = wid * 64 + ct * 16 + g4 * 4;
        f32x4 bb = *reinterpret_cast<const f32x4*>(&bias[ch]);
        #pragma unroll
        for (int rt = 0; rt < 2; ++rt) {
            int tokL = rt * 16 + r16;
            f32x4 rb = *reinterpret_cast<const f32x4*>(&rsd[tokL][ch]);
            f32x4 vv;
            #pragma unroll
            for (int rr = 0; rr < 4; ++rr) {
                float val = acc[ct][rt][rr] + bb[rr];
                vv[rr] = 0.5f * val * (1.0f + erff(val * 0.70710678118654752f)) + rb[rr];
            }
            *reinterpret_cast<f32x4*>(out + (size_t)(tok0 + tokL) * CH + ch) = vv;
        }
    }
}

extern "C" void kernel_launch(void* const* d_in, const int* in_sizes, int n_in,
                              void* d_out, int out_size, void* d_ws, size_t ws_size,
                              hipStream_t stream)
{
    const float* x     = (const float*)d_in[0];
    const float* ln_g  = (const float*)d_in[1];
    const float* ln_b  = (const float*)d_in[2];
    const float* wq_w  = (const float*)d_in[3];
    const float* wq_b  = (const float*)d_in[4];
    const float* wk_w  = (const float*)d_in[5];
    const float* wk_b  = (const float*)d_in[6];
    const float* wv_w  = (const float*)d_in[7];
    const float* wv_b  = (const float*)d_in[8];
    const float* mlp_w = (const float*)d_in[9];
    const float* mlp_b = (const float*)d_in[10];

    char* ws = (char*)d_ws;
    u16* wcat = (u16*)ws;                       // 768*256 bf16
    u16* wmb  = (u16*)(ws + 393216);            // 256*256 bf16
    u16* xnq  = (u16*)(ws + 524288);            // xn -> q (in-place) -> attn output
    u16* kbuf = (u16*)d_out;                    // k,v live in d_out until K3 rewrites it
    u16* vbuf = (u16*)d_out + (size_t)NTOK * CH;

    swa_prep <<<256,  256, 0, stream>>>(wq_w, wk_w, wv_w, mlp_w, wcat, wmb);
    swa_ln   <<<1568, 256, 0, stream>>>(x, ln_g, ln_b, xnq);
    swa_kv   <<<1568, 512, 0, stream>>>(xnq, wcat, wk_b, wv_b, kbuf, vbuf);
    swa_q    <<<392,  512, 0, stream>>>(xnq, wcat, wq_b);
    swa_attn <<<3584, 256, 0, stream>>>(xnq, kbuf, vbuf, xnq);
    swa_mlp4 <<<3136, 256, 0, stream>>>(x, xnq, ln_g, ln_b, wmb, mlp_b, (float*)d_out);
}